// Round 4
// baseline (401.320 us; speedup 1.0000x reference)
//
#include <hip/hip_runtime.h>

#define N_AB  1024
#define NHALF 1025
#define NFULL 2049
#define HDIM  64
#define PLANE ((size_t)N_AB * NFULL)
#define C2L   2.8853900817779268f   // 2*log2(e)
#define TLN2  1.3862943611198906f   // 2*ln(2);  C2L * TLN2 = 4

typedef __bf16 bf16x8 __attribute__((ext_vector_type(8)));
typedef __bf16 bf16x4 __attribute__((ext_vector_type(4)));
typedef float  f32x4  __attribute__((ext_vector_type(4)));

#define MFMA16(A,B,C) __builtin_amdgcn_mfma_f32_16x16x32_bf16(A,B,C,0,0,0)

// S = z * 2*log2e ; H = tanh(z) ; T = u - u^2 with u = 1/(1+2^S) ; note 1-H^2 = 4T.
// Graceful at +/-inf: exp2->inf => u=0 => H=1 ; exp2->0 => u=1 => H=-1. No clamp needed.
#define ACT1(S,H,T) { float _e = __builtin_amdgcn_exp2f(S); \
                      float _u = __builtin_amdgcn_rcpf(1.0f + _e); \
                      H = fmaf(-2.0f,_u,1.0f); T = fmaf(-_u,_u,_u); }

// one layer-1 element: WC = w0*C2L, BC = b0*C2L ; packs h->BV[IDX], dh=4t*w0 -> BT[IDX]
// (t*WC*TLN2 == 4*t*w0 exactly in intent; 2 muls instead of keeping a 4*w0 register quad)
#define L1E(IDX, WC, BC, BV, BT) { float _s = fmaf(WC, x, BC); float _h,_t; \
                      ACT1(_s,_h,_t) \
                      BV[IDX] = (__bf16)_h; BT[IDX] = (__bf16)((_t * (WC)) * TLN2); }

#define L1OCT(WA,WB,BA,BB,BV,BT) \
    L1E(0, WA.x, BA.x, BV, BT) \
    L1E(1, WA.y, BA.y, BV, BT) \
    L1E(2, WA.z, BA.z, BV, BT) \
    L1E(3, WA.w, BA.w, BV, BT) \
    L1E(4, WB.x, BB.x, BV, BT) \
    L1E(5, WB.y, BB.y, BV, BT) \
    L1E(6, WB.z, BB.z, BV, BT) \
    L1E(7, WB.w, BB.w, BV, BT)

// one layer-2 element: ACC=z2pre, DACC=dz2pre, B1C=b1*C2L ; accumulates layer-3 partials.
// dh carries T*dacc only; the missing *4 is folded into da/db (8.0f factor) later.
#define L2E(ACC,DACC,B1C,W20,W21) { \
    float _s = fmaf(ACC, C2L, B1C); float _h,_t; ACT1(_s,_h,_t) \
    float _dh = _t * (DACC); \
    pv0 = fmaf(W20,_h,pv0); pv1 = fmaf(W21,_h,pv1); \
    pt0 = fmaf(W20,_dh,pt0); pt1 = fmaf(W21,_dh,pt1); }

#define L2RT(AV,AT,B1,WR0,WR1) \
    L2E(AV[0],AT[0],B1.x,WR0.x,WR1.x) \
    L2E(AV[1],AT[1],B1.y,WR0.y,WR1.y) \
    L2E(AV[2],AT[2],B1.z,WR0.z,WR1.z) \
    L2E(AV[3],AT[3],B1.w,WR0.w,WR1.w)

#define SC4(V,S) { V.x*=(S); V.y*=(S); V.z*=(S); V.w*=(S); }

// full per-point-tile pipeline; P = point index; leaves xp,yp,xpp,ypp in scope
#define COMPUTE_TILE(P) \
    const float4 tg = s_trig[P]; \
    const float x = tg.x, sa = tg.y, cam1 = tg.z; \
    const float ca = cam1 + 1.0f; \
    bf16x8 bv0, bv1, bt0, bt1; \
    L1OCT(w0A,w0B,b0A,b0B,bv0,bt0) \
    L1OCT(w0C,w0D,b0C,b0D,bv1,bt1) \
    const f32x4 zz = {0.0f,0.0f,0.0f,0.0f}; \
    f32x4 av0 = MFMA16(A01,bv1,MFMA16(A00,bv0,zz)); \
    f32x4 av1 = MFMA16(A11,bv1,MFMA16(A10,bv0,zz)); \
    f32x4 av2 = MFMA16(A21,bv1,MFMA16(A20,bv0,zz)); \
    f32x4 av3 = MFMA16(A31,bv1,MFMA16(A30,bv0,zz)); \
    f32x4 at0 = MFMA16(A01,bt1,MFMA16(A00,bt0,zz)); \
    f32x4 at1 = MFMA16(A11,bt1,MFMA16(A10,bt0,zz)); \
    f32x4 at2 = MFMA16(A21,bt1,MFMA16(A20,bt0,zz)); \
    f32x4 at3 = MFMA16(A31,bt1,MFMA16(A30,bt0,zz)); \
    float pv0=0.0f,pv1=0.0f,pt0=0.0f,pt1=0.0f; \
    L2RT(av0,at0,b1c0,w2a0,w2b0) \
    L2RT(av1,at1,b1c1,w2a1,w2b1) \
    L2RT(av2,at2,b1c2,w2a2,w2b2) \
    L2RT(av3,at3,b1c3,w2a3,w2b3) \
    pv0 += __shfl_xor(pv0,16); pv0 += __shfl_xor(pv0,32); \
    pv1 += __shfl_xor(pv1,16); pv1 += __shfl_xor(pv1,32); \
    pt0 += __shfl_xor(pt0,16); pt0 += __shfl_xor(pt0,32); \
    pt1 += __shfl_xor(pt1,16); pt1 += __shfl_xor(pt1,32); \
    const float z0 = pv0 + b20, z1 = pv1 + b21; \
    const float aa = z0*z0, bb = z1*z1; \
    const float da = 8.0f*z0*pt0, db = 8.0f*z1*pt1; \
    const float xp = aa*cam1, yp = bb*sa; \
    const float xpp = fmaf(da,cam1,-(aa*sa)); \
    const float ypp = fmaf(bb,ca, db*sa);

__global__ void __launch_bounds__(256, 6) sofa_kernel(
    const float* __restrict__ alpha,
    const float* __restrict__ w0,
    const float* __restrict__ w1,
    const float* __restrict__ w2,
    const float* __restrict__ b0,
    const float* __restrict__ b1,
    const float* __restrict__ b2,
    float* __restrict__ out)
{
    __shared__ __align__(16) __bf16 w1s[HDIM * HDIM];   // XOR-swizzled bf16 W1
    __shared__ __align__(16) float4 s_trig[NHALF];      // {x, sin x, cos x - 1, 0}
    __shared__ float s_xplast;

    const int n    = blockIdx.x;
    const int half = blockIdx.y;        // 0: points 0..511, 1: points 512..1023
    const int tid  = threadIdx.x;
    const int lane = tid & 63;
    const int wid  = tid >> 6;
    const int col  = lane & 15;   // MFMA col (point) / A-row index
    const int grp  = lane >> 4;   // k-slot group / output-plane selector

    const float* __restrict__ w0n = w0 + (size_t)n * HDIM;
    const float* __restrict__ b0n = b0 + (size_t)n * HDIM;
    const float* __restrict__ w1n = w1 + (size_t)n * HDIM * HDIM;
    const float* __restrict__ b1n = b1 + (size_t)n * HDIM;
    const float* __restrict__ w2n = w2 + (size_t)n * 2 * HDIM;
    const float* __restrict__ b2n = b2 + (size_t)n * 2;

    // ---- stage trig table and W1 (bf16, 16B-group XOR swizzle) into LDS ----
    for (int e = tid; e < NHALF; e += 256) {
        float xx = alpha[e];
        float4 t;
        t.x = xx; t.y = __sinf(xx); t.z = __cosf(xx) - 1.0f; t.w = 0.0f;
        s_trig[e] = t;
    }
    for (int e4 = tid; e4 < (HDIM * HDIM) / 4; e4 += 256) {
        const int i = e4 >> 4, j4 = (e4 & 15) << 2;
        float4 v = ((const float4*)w1n)[e4];
        bf16x4 b;
        b[0] = (__bf16)v.x; b[1] = (__bf16)v.y; b[2] = (__bf16)v.z; b[3] = (__bf16)v.w;
        *(bf16x4*)&w1s[i * 64 + (((j4 >> 3) ^ (i & 7)) << 3) + (j4 & 7)] = b;
    }
    __syncthreads();

    // ---- per-lane hoisted constants (named scalars / float4 -> SSA, no allocas) ----
    const int jb0 = grp * 8, jb1 = 32 + grp * 8;
    float4 w0A = *(const float4*)(w0n + jb0);
    float4 w0B = *(const float4*)(w0n + jb0 + 4);
    float4 w0C = *(const float4*)(w0n + jb1);
    float4 w0D = *(const float4*)(w0n + jb1 + 4);
    SC4(w0A, C2L)  SC4(w0B, C2L)  SC4(w0C, C2L)  SC4(w0D, C2L)
    float4 b0A = *(const float4*)(b0n + jb0);
    float4 b0B = *(const float4*)(b0n + jb0 + 4);
    float4 b0C = *(const float4*)(b0n + jb1);
    float4 b0D = *(const float4*)(b0n + jb1 + 4);
    SC4(b0A, C2L) SC4(b0B, C2L) SC4(b0C, C2L) SC4(b0D, C2L)

    float4 b1c0 = *(const float4*)(b1n + 0  + grp * 4);
    float4 b1c1 = *(const float4*)(b1n + 16 + grp * 4);
    float4 b1c2 = *(const float4*)(b1n + 32 + grp * 4);
    float4 b1c3 = *(const float4*)(b1n + 48 + grp * 4);
    SC4(b1c0, C2L) SC4(b1c1, C2L) SC4(b1c2, C2L) SC4(b1c3, C2L)

    const float4 w2a0 = *(const float4*)(w2n + 0  + grp * 4);
    const float4 w2a1 = *(const float4*)(w2n + 16 + grp * 4);
    const float4 w2a2 = *(const float4*)(w2n + 32 + grp * 4);
    const float4 w2a3 = *(const float4*)(w2n + 48 + grp * 4);
    const float4 w2b0 = *(const float4*)(w2n + 64 + 0  + grp * 4);
    const float4 w2b1 = *(const float4*)(w2n + 64 + 16 + grp * 4);
    const float4 w2b2 = *(const float4*)(w2n + 64 + 32 + grp * 4);
    const float4 w2b3 = *(const float4*)(w2n + 64 + 48 + grp * 4);
    const float b20 = b2n[0], b21 = b2n[1];

    // ---- A-fragments: W1 rows in registers (lane: row=col, k = 32*KH + 8*grp + 0..7) ----
    const bf16x8* w1v = (const bf16x8*)w1s;
    const int sw = col & 7;
#define AF(RT,KH) w1v[((RT)*16 + col)*8 + (((KH)*4 + grp) ^ sw)]
    const bf16x8 A00 = AF(0,0), A01 = AF(0,1), A10 = AF(1,0), A11 = AF(1,1);
    const bf16x8 A20 = AF(2,0), A21 = AF(2,1), A30 = AF(3,0), A31 = AF(3,1);

    const size_t obase = (size_t)grp * PLANE + (size_t)n * NFULL;

    // ---- point 1024 first (wave 0), to get xp_last for the xp mirror ----
    // (both half-blocks compute it; identical deterministic value, benign dup store)
    if (wid == 0) {
        COMPUTE_TILE(1024)
        if (col == 0) {
            out[obase + 1024] = (grp == 0) ? xp : (grp == 1) ? yp : (grp == 2) ? xpp : ypp;
            if (grp == 0) s_xplast = xp;
        }
    }
    __syncthreads();
    const float xl2 = 2.0f * s_xplast;

    // ---- main loop: 8 iters/wave, 16 points each; this block covers 512 points ----
    const int poff = half << 9;
    #pragma unroll 1
    for (int it = 0; it < 8; ++it) {
        const int p = poff + (it << 6) + (wid << 4) + col;
        COMPUTE_TILE(p)
        const float vdir = (grp == 0) ? xp : (grp == 1) ? yp : (grp == 2) ? xpp : ypp;
        const float vmir = (grp == 0) ? (xl2 - xp)
                         : (grp == 1) ? yp
                         : (grp == 2) ? xpp : -ypp;
        out[obase + p] = vdir;
        out[obase + (2048 - p)] = vmir;
    }
}

extern "C" void kernel_launch(void* const* d_in, const int* in_sizes, int n_in,
                              void* d_out, int out_size, void* d_ws, size_t ws_size,
                              hipStream_t stream) {
    const float* alpha = (const float*)d_in[0];
    const float* w0    = (const float*)d_in[1];
    const float* w1    = (const float*)d_in[2];
    const float* w2    = (const float*)d_in[3];
    const float* b0    = (const float*)d_in[4];
    const float* b1    = (const float*)d_in[5];
    const float* b2    = (const float*)d_in[6];
    float* out = (float*)d_out;
    sofa_kernel<<<dim3(N_AB, 2), dim3(256), 0, stream>>>(alpha, w0, w1, w2, b0, b1, b2, out);
}

// Round 5
// 71.915 us; speedup vs baseline: 5.5805x; 5.5805x over previous
//
#include <hip/hip_runtime.h>

#define N_AB  1024
#define NHALF 1025
#define NFULL 2049
#define HDIM  64
#define PLANE ((size_t)N_AB * NFULL)
#define C2L   2.8853900817779268f   // 2*log2(e)
#define TLN2  1.3862943611198906f   // 2*ln(2);  C2L * TLN2 = 4

typedef __bf16 bf16x8 __attribute__((ext_vector_type(8)));
typedef __bf16 bf16x4 __attribute__((ext_vector_type(4)));
typedef float  f32x4  __attribute__((ext_vector_type(4)));

#define MFMA16(A,B,C) __builtin_amdgcn_mfma_f32_16x16x32_bf16(A,B,C,0,0,0)

// S = z * 2*log2e ; H = tanh(z) ; T = u - u^2 with u = 1/(1+2^S) ; note 1-H^2 = 4T.
// Graceful at +/-inf: exp2->inf => u=0 => H=1 ; exp2->0 => u=1 => H=-1. No clamp needed.
#define ACT1(S,H,T) { float _e = __builtin_amdgcn_exp2f(S); \
                      float _u = __builtin_amdgcn_rcpf(1.0f + _e); \
                      H = fmaf(-2.0f,_u,1.0f); T = fmaf(-_u,_u,_u); }

// one layer-1 element: WC = w0*C2L, BC = b0*C2L ; packs h->BV[IDX], dh=4t*w0 -> BT[IDX]
#define L1E(IDX, WC, BC, BV, BT) { float _s = fmaf(WC, x, BC); float _h,_t; \
                      ACT1(_s,_h,_t) \
                      BV[IDX] = (__bf16)_h; BT[IDX] = (__bf16)((_t * (WC)) * TLN2); }

#define L1OCT(WA,WB,BA,BB,BV,BT) \
    L1E(0, WA.x, BA.x, BV, BT) \
    L1E(1, WA.y, BA.y, BV, BT) \
    L1E(2, WA.z, BA.z, BV, BT) \
    L1E(3, WA.w, BA.w, BV, BT) \
    L1E(4, WB.x, BB.x, BV, BT) \
    L1E(5, WB.y, BB.y, BV, BT) \
    L1E(6, WB.z, BB.z, BV, BT) \
    L1E(7, WB.w, BB.w, BV, BT)

// one layer-2 element: ACC=z2pre, DACC=dz2pre, B1C=b1*C2L ; accumulates layer-3 partials.
// dh carries T*dacc only; the missing *4 is folded into da/db (8.0f factor) later.
#define L2E(ACC,DACC,B1C,W20,W21) { \
    float _s = fmaf(ACC, C2L, B1C); float _h,_t; ACT1(_s,_h,_t) \
    float _dh = _t * (DACC); \
    pv0 = fmaf(W20,_h,pv0); pv1 = fmaf(W21,_h,pv1); \
    pt0 = fmaf(W20,_dh,pt0); pt1 = fmaf(W21,_dh,pt1); }

#define L2RT(AV,AT,B1,WR0,WR1) \
    L2E(AV[0],AT[0],B1.x,WR0.x,WR1.x) \
    L2E(AV[1],AT[1],B1.y,WR0.y,WR1.y) \
    L2E(AV[2],AT[2],B1.z,WR0.z,WR1.z) \
    L2E(AV[3],AT[3],B1.w,WR0.w,WR1.w)

#define SC4(V,S) { V.x*=(S); V.y*=(S); V.z*=(S); V.w*=(S); }

// full per-point-tile pipeline; P = point index; leaves xp,yp,xpp,ypp in scope
#define COMPUTE_TILE(P) \
    const float4 tg = s_trig[P]; \
    const float sa = tg.y, cam1 = tg.z; \
    const float x = tg.x; \
    const float ca = cam1 + 1.0f; \
    bf16x8 bv0, bv1, bt0, bt1; \
    L1OCT(w0A,w0B,b0A,b0B,bv0,bt0) \
    L1OCT(w0C,w0D,b0C,b0D,bv1,bt1) \
    const f32x4 zz = {0.0f,0.0f,0.0f,0.0f}; \
    f32x4 av0 = MFMA16(A01,bv1,MFMA16(A00,bv0,zz)); \
    f32x4 av1 = MFMA16(A11,bv1,MFMA16(A10,bv0,zz)); \
    f32x4 av2 = MFMA16(A21,bv1,MFMA16(A20,bv0,zz)); \
    f32x4 av3 = MFMA16(A31,bv1,MFMA16(A30,bv0,zz)); \
    f32x4 at0 = MFMA16(A01,bt1,MFMA16(A00,bt0,zz)); \
    f32x4 at1 = MFMA16(A11,bt1,MFMA16(A10,bt0,zz)); \
    f32x4 at2 = MFMA16(A21,bt1,MFMA16(A20,bt0,zz)); \
    f32x4 at3 = MFMA16(A31,bt1,MFMA16(A30,bt0,zz)); \
    float pv0=0.0f,pv1=0.0f,pt0=0.0f,pt1=0.0f; \
    L2RT(av0,at0,b1c0,w2a0,w2b0) \
    L2RT(av1,at1,b1c1,w2a1,w2b1) \
    L2RT(av2,at2,b1c2,w2a2,w2b2) \
    L2RT(av3,at3,b1c3,w2a3,w2b3) \
    pv0 += __shfl_xor(pv0,16); pv0 += __shfl_xor(pv0,32); \
    pv1 += __shfl_xor(pv1,16); pv1 += __shfl_xor(pv1,32); \
    pt0 += __shfl_xor(pt0,16); pt0 += __shfl_xor(pt0,32); \
    pt1 += __shfl_xor(pt1,16); pt1 += __shfl_xor(pt1,32); \
    const float z0 = pv0 + b20, z1 = pv1 + b21; \
    const float aa = z0*z0, bb = z1*z1; \
    const float da = 8.0f*z0*pt0, db = 8.0f*z1*pt1; \
    const float xp = aa*cam1, yp = bb*sa; \
    const float xpp = fmaf(da,cam1,-(aa*sa)); \
    const float ypp = fmaf(bb,ca, db*sa);

__global__ void __launch_bounds__(256, 2) sofa_kernel(   // (256,2): proven no-spill setting (R3)
    const float* __restrict__ alpha,
    const float* __restrict__ w0,
    const float* __restrict__ w1,
    const float* __restrict__ w2,
    const float* __restrict__ b0,
    const float* __restrict__ b1,
    const float* __restrict__ b2,
    float* __restrict__ out)
{
    __shared__ __align__(16) __bf16 w1s[HDIM * HDIM];   // XOR-swizzled bf16 W1
    __shared__ __align__(16) float4 s_trig[NHALF];      // {x, sin x, cos x - 1, 0}
    __shared__ float s_xplast;

    const int n    = blockIdx.x;
    const int half = blockIdx.y;        // 0: points 0..511, 1: points 512..1023
    const int tid  = threadIdx.x;
    const int lane = tid & 63;
    const int wid  = tid >> 6;
    const int col  = lane & 15;   // MFMA col (point) / A-row index
    const int grp  = lane >> 4;   // k-slot group / output-plane selector

    const float* __restrict__ w0n = w0 + (size_t)n * HDIM;
    const float* __restrict__ b0n = b0 + (size_t)n * HDIM;
    const float* __restrict__ w1n = w1 + (size_t)n * HDIM * HDIM;
    const float* __restrict__ b1n = b1 + (size_t)n * HDIM;
    const float* __restrict__ w2n = w2 + (size_t)n * 2 * HDIM;
    const float* __restrict__ b2n = b2 + (size_t)n * 2;

    // ---- stage trig table and W1 (bf16, 16B-group XOR swizzle) into LDS ----
    for (int e = tid; e < NHALF; e += 256) {
        float xx = alpha[e];
        float4 t;
        t.x = xx; t.y = __sinf(xx); t.z = __cosf(xx) - 1.0f; t.w = 0.0f;
        s_trig[e] = t;
    }
    for (int e4 = tid; e4 < (HDIM * HDIM) / 4; e4 += 256) {
        const int i = e4 >> 4, j4 = (e4 & 15) << 2;
        float4 v = ((const float4*)w1n)[e4];
        bf16x4 b;
        b[0] = (__bf16)v.x; b[1] = (__bf16)v.y; b[2] = (__bf16)v.z; b[3] = (__bf16)v.w;
        *(bf16x4*)&w1s[i * 64 + (((j4 >> 3) ^ (i & 7)) << 3) + (j4 & 7)] = b;
    }
    __syncthreads();

    // ---- per-lane hoisted constants (named scalars / float4 -> SSA, no allocas) ----
    const int jb0 = grp * 8, jb1 = 32 + grp * 8;
    float4 w0A = *(const float4*)(w0n + jb0);
    float4 w0B = *(const float4*)(w0n + jb0 + 4);
    float4 w0C = *(const float4*)(w0n + jb1);
    float4 w0D = *(const float4*)(w0n + jb1 + 4);
    SC4(w0A, C2L)  SC4(w0B, C2L)  SC4(w0C, C2L)  SC4(w0D, C2L)
    float4 b0A = *(const float4*)(b0n + jb0);
    float4 b0B = *(const float4*)(b0n + jb0 + 4);
    float4 b0C = *(const float4*)(b0n + jb1);
    float4 b0D = *(const float4*)(b0n + jb1 + 4);
    SC4(b0A, C2L) SC4(b0B, C2L) SC4(b0C, C2L) SC4(b0D, C2L)

    float4 b1c0 = *(const float4*)(b1n + 0  + grp * 4);
    float4 b1c1 = *(const float4*)(b1n + 16 + grp * 4);
    float4 b1c2 = *(const float4*)(b1n + 32 + grp * 4);
    float4 b1c3 = *(const float4*)(b1n + 48 + grp * 4);
    SC4(b1c0, C2L) SC4(b1c1, C2L) SC4(b1c2, C2L) SC4(b1c3, C2L)

    const float4 w2a0 = *(const float4*)(w2n + 0  + grp * 4);
    const float4 w2a1 = *(const float4*)(w2n + 16 + grp * 4);
    const float4 w2a2 = *(const float4*)(w2n + 32 + grp * 4);
    const float4 w2a3 = *(const float4*)(w2n + 48 + grp * 4);
    const float4 w2b0 = *(const float4*)(w2n + 64 + 0  + grp * 4);
    const float4 w2b1 = *(const float4*)(w2n + 64 + 16 + grp * 4);
    const float4 w2b2 = *(const float4*)(w2n + 64 + 32 + grp * 4);
    const float4 w2b3 = *(const float4*)(w2n + 64 + 48 + grp * 4);
    const float b20 = b2n[0], b21 = b2n[1];

    // ---- A-fragments: W1 rows in registers (lane: row=col, k = 32*KH + 8*grp + 0..7) ----
    const bf16x8* w1v = (const bf16x8*)w1s;
    const int sw = col & 7;
#define AF(RT,KH) w1v[((RT)*16 + col)*8 + (((KH)*4 + grp) ^ sw)]
    const bf16x8 A00 = AF(0,0), A01 = AF(0,1), A10 = AF(1,0), A11 = AF(1,1);
    const bf16x8 A20 = AF(2,0), A21 = AF(2,1), A30 = AF(3,0), A31 = AF(3,1);

    const size_t obase = (size_t)grp * PLANE + (size_t)n * NFULL;

    // ---- point 1024 first (wave 0), to get xp_last for the xp mirror ----
    // (both half-blocks compute it; identical deterministic value, benign dup store)
    if (wid == 0) {
        COMPUTE_TILE(1024)
        if (col == 0) {
            out[obase + 1024] = (grp == 0) ? xp : (grp == 1) ? yp : (grp == 2) ? xpp : ypp;
            if (grp == 0) s_xplast = xp;
        }
    }
    __syncthreads();
    const float xl2 = 2.0f * s_xplast;

    // ---- main loop: 8 iters/wave, 16 points each; this block covers 512 points ----
    const int poff = half << 9;
    #pragma unroll 1
    for (int it = 0; it < 8; ++it) {
        const int p = poff + (it << 6) + (wid << 4) + col;
        COMPUTE_TILE(p)
        const float vdir = (grp == 0) ? xp : (grp == 1) ? yp : (grp == 2) ? xpp : ypp;
        const float vmir = (grp == 0) ? (xl2 - xp)
                         : (grp == 1) ? yp
                         : (grp == 2) ? xpp : -ypp;
        out[obase + p] = vdir;
        out[obase + (2048 - p)] = vmir;
    }
}

extern "C" void kernel_launch(void* const* d_in, const int* in_sizes, int n_in,
                              void* d_out, int out_size, void* d_ws, size_t ws_size,
                              hipStream_t stream) {
    const float* alpha = (const float*)d_in[0];
    const float* w0    = (const float*)d_in[1];
    const float* w1    = (const float*)d_in[2];
    const float* w2    = (const float*)d_in[3];
    const float* b0    = (const float*)d_in[4];
    const float* b1    = (const float*)d_in[5];
    const float* b2    = (const float*)d_in[6];
    float* out = (float*)d_out;
    sofa_kernel<<<dim3(N_AB, 2), dim3(256), 0, stream>>>(alpha, w0, w1, w2, b0, b1, b2, out);
}

// Round 6
// 57.402 us; speedup vs baseline: 6.9914x; 1.2528x over previous
//
#include <hip/hip_runtime.h>

#define N_AB  1024
#define NHALF 1025
#define NFULL 2049
#define HDIM  64
#define PLANE ((size_t)N_AB * NFULL)
#define C2L   2.8853900817779268f   // 2*log2(e)
#define TLN2  1.3862943611198906f   // 2*ln(2);  C2L * TLN2 = 4

typedef __bf16 bf16x8 __attribute__((ext_vector_type(8)));
typedef __bf16 bf16x4 __attribute__((ext_vector_type(4)));
typedef float  f32x4  __attribute__((ext_vector_type(4)));
typedef float  f32x2  __attribute__((ext_vector_type(2)));

#define MFMA16(A,B,C) __builtin_amdgcn_mfma_f32_16x16x32_bf16(A,B,C,0,0,0)

// Packed (float2) tanh core: S2 = z*2log2e (pair). H2 = tanh(z), T2 = u-u^2 (1-H^2 = 4T).
// Regular ops are f32x2 -> v_pk_* VOP3P; exp2/rcp stay scalar (no packed transcendentals).
#define ACT2(S2,H2,T2) { \
    f32x2 _e; _e.x = __builtin_amdgcn_exp2f(S2.x); _e.y = __builtin_amdgcn_exp2f(S2.y); \
    f32x2 _d = _e + 1.0f; \
    f32x2 _u; _u.x = __builtin_amdgcn_rcpf(_d.x); _u.y = __builtin_amdgcn_rcpf(_d.y); \
    H2 = __builtin_elementwise_fma(_km2, _u, _k1); \
    T2 = __builtin_elementwise_fma(-_u, _u, _u); }

// layer-1 element pair: WC2 = w0*C2L, BC2 = b0*C2L ; h -> BV[I0..I0+1], 4t*w0 -> BT
#define L1P(I0, WC2, BC2, BV, BT) { \
    f32x2 _s = __builtin_elementwise_fma(WC2, x2, BC2); \
    f32x2 _h, _t; ACT2(_s,_h,_t) \
    f32x2 _bt = (_t * WC2) * TLN2; \
    BV[I0] = (__bf16)_h.x; BV[I0+1] = (__bf16)_h.y; \
    BT[I0] = (__bf16)_bt.x; BT[I0+1] = (__bf16)_bt.y; }

// layer-2 element pair: AV2=z2pre, AT2=dz2pre, B1C2=b1*C2L ; accumulate L3 partial pairs.
// _dh carries t*dacc only; missing *4 folded into the 8.0f in da/db.
#define L2P(AV2, AT2, B1C2, W20_2, W21_2) { \
    f32x2 _s = __builtin_elementwise_fma(AV2, c2l2, B1C2); \
    f32x2 _h, _t; ACT2(_s,_h,_t) \
    f32x2 _dh = _t * (AT2); \
    pv0_2 = __builtin_elementwise_fma(W20_2, _h,  pv0_2); \
    pv1_2 = __builtin_elementwise_fma(W21_2, _h,  pv1_2); \
    pt0_2 = __builtin_elementwise_fma(W20_2, _dh, pt0_2); \
    pt1_2 = __builtin_elementwise_fma(W21_2, _dh, pt1_2); }

#define L2QUAD(AV,AT,B1,WR0,WR1) \
    L2P(AV.xy, AT.xy, B1.xy, WR0.xy, WR1.xy) \
    L2P(AV.zw, AT.zw, B1.zw, WR0.zw, WR1.zw)

// full per-point-tile pipeline; leaves xp,yp,xpp,ypp in scope
#define COMPUTE_TILE(XV) \
    const float x = (XV); \
    const f32x2 x2 = {x, x}; \
    const float sa = __sinf(x), ca = __cosf(x); \
    const float cam1 = ca - 1.0f; \
    bf16x8 bv0, bv1, bt0, bt1; \
    L1P(0, w0A.xy, b0A.xy, bv0, bt0) \
    L1P(2, w0A.zw, b0A.zw, bv0, bt0) \
    L1P(4, w0B.xy, b0B.xy, bv0, bt0) \
    L1P(6, w0B.zw, b0B.zw, bv0, bt0) \
    L1P(0, w0C.xy, b0C.xy, bv1, bt1) \
    L1P(2, w0C.zw, b0C.zw, bv1, bt1) \
    L1P(4, w0D.xy, b0D.xy, bv1, bt1) \
    L1P(6, w0D.zw, b0D.zw, bv1, bt1) \
    const f32x4 zz = {0.0f,0.0f,0.0f,0.0f}; \
    f32x4 av0 = MFMA16(A01,bv1,MFMA16(A00,bv0,zz)); \
    f32x4 av1 = MFMA16(A11,bv1,MFMA16(A10,bv0,zz)); \
    f32x4 av2 = MFMA16(A21,bv1,MFMA16(A20,bv0,zz)); \
    f32x4 av3 = MFMA16(A31,bv1,MFMA16(A30,bv0,zz)); \
    f32x4 at0 = MFMA16(A01,bt1,MFMA16(A00,bt0,zz)); \
    f32x4 at1 = MFMA16(A11,bt1,MFMA16(A10,bt0,zz)); \
    f32x4 at2 = MFMA16(A21,bt1,MFMA16(A20,bt0,zz)); \
    f32x4 at3 = MFMA16(A31,bt1,MFMA16(A30,bt0,zz)); \
    f32x2 pv0_2 = {0.0f,0.0f}, pv1_2 = {0.0f,0.0f}; \
    f32x2 pt0_2 = {0.0f,0.0f}, pt1_2 = {0.0f,0.0f}; \
    L2QUAD(av0,at0,b1c0,w2a0,w2b0) \
    L2QUAD(av1,at1,b1c1,w2a1,w2b1) \
    L2QUAD(av2,at2,b1c2,w2a2,w2b2) \
    L2QUAD(av3,at3,b1c3,w2a3,w2b3) \
    float pv0 = pv0_2.x + pv0_2.y, pv1 = pv1_2.x + pv1_2.y; \
    float pt0 = pt0_2.x + pt0_2.y, pt1 = pt1_2.x + pt1_2.y; \
    pv0 += __shfl_xor(pv0,16); pv0 += __shfl_xor(pv0,32); \
    pv1 += __shfl_xor(pv1,16); pv1 += __shfl_xor(pv1,32); \
    pt0 += __shfl_xor(pt0,16); pt0 += __shfl_xor(pt0,32); \
    pt1 += __shfl_xor(pt1,16); pt1 += __shfl_xor(pt1,32); \
    const float z0 = pv0 + b20, z1 = pv1 + b21; \
    const float aa = z0*z0, bb = z1*z1; \
    const float da = 8.0f*z0*pt0, db = 8.0f*z1*pt1; \
    const float xp = aa*cam1, yp = bb*sa; \
    const float xpp = fmaf(da,cam1,-(aa*sa)); \
    const float ypp = fmaf(bb,ca, db*sa);

__global__ void __launch_bounds__(256, 2) sofa_kernel(   // (256,2): proven no-spill setting (R3)
    const float* __restrict__ alpha,
    const float* __restrict__ w0,
    const float* __restrict__ w1,
    const float* __restrict__ w2,
    const float* __restrict__ b0,
    const float* __restrict__ b1,
    const float* __restrict__ b2,
    float* __restrict__ out)
{
    __shared__ __align__(16) __bf16 w1s[HDIM * HDIM];   // XOR-swizzled bf16 W1
    __shared__ float s_alpha[NHALF];
    __shared__ float s_xplast;

    const int n    = blockIdx.x;
    const int tid  = threadIdx.x;
    const int lane = tid & 63;
    const int wid  = tid >> 6;
    const int col  = lane & 15;   // MFMA col (point) / A-row index
    const int grp  = lane >> 4;   // k-slot group / output-plane selector

    const float* __restrict__ w0n = w0 + (size_t)n * HDIM;
    const float* __restrict__ b0n = b0 + (size_t)n * HDIM;
    const float* __restrict__ w1n = w1 + (size_t)n * HDIM * HDIM;
    const float* __restrict__ b1n = b1 + (size_t)n * HDIM;
    const float* __restrict__ w2n = w2 + (size_t)n * 2 * HDIM;
    const float* __restrict__ b2n = b2 + (size_t)n * 2;

    // ---- stage alpha (fp32) and W1 (bf16, 16B-group XOR swizzle) into LDS ----
    for (int e = tid; e < NHALF; e += 256) s_alpha[e] = alpha[e];
    for (int e4 = tid; e4 < (HDIM * HDIM) / 4; e4 += 256) {
        const int i = e4 >> 4, j4 = (e4 & 15) << 2;
        f32x4 v = ((const f32x4*)w1n)[e4];
        bf16x4 b;
        b[0] = (__bf16)v.x; b[1] = (__bf16)v.y; b[2] = (__bf16)v.z; b[3] = (__bf16)v.w;
        *(bf16x4*)&w1s[i * 64 + (((j4 >> 3) ^ (i & 7)) << 3) + (j4 & 7)] = b;
    }
    __syncthreads();

    // ---- constants for packed math ----
    const f32x2 _km2 = {-2.0f, -2.0f};
    const f32x2 _k1  = { 1.0f,  1.0f};
    const f32x2 c2l2 = { C2L,   C2L };

    // ---- per-lane hoisted constants (named ext-vectors -> SSA, no allocas) ----
    const int jb0 = grp * 8, jb1 = 32 + grp * 8;
    f32x4 w0A = *(const f32x4*)(w0n + jb0);
    f32x4 w0B = *(const f32x4*)(w0n + jb0 + 4);
    f32x4 w0C = *(const f32x4*)(w0n + jb1);
    f32x4 w0D = *(const f32x4*)(w0n + jb1 + 4);
    w0A *= C2L; w0B *= C2L; w0C *= C2L; w0D *= C2L;
    f32x4 b0A = *(const f32x4*)(b0n + jb0);
    f32x4 b0B = *(const f32x4*)(b0n + jb0 + 4);
    f32x4 b0C = *(const f32x4*)(b0n + jb1);
    f32x4 b0D = *(const f32x4*)(b0n + jb1 + 4);
    b0A *= C2L; b0B *= C2L; b0C *= C2L; b0D *= C2L;

    f32x4 b1c0 = *(const f32x4*)(b1n + 0  + grp * 4);
    f32x4 b1c1 = *(const f32x4*)(b1n + 16 + grp * 4);
    f32x4 b1c2 = *(const f32x4*)(b1n + 32 + grp * 4);
    f32x4 b1c3 = *(const f32x4*)(b1n + 48 + grp * 4);
    b1c0 *= C2L; b1c1 *= C2L; b1c2 *= C2L; b1c3 *= C2L;

    const f32x4 w2a0 = *(const f32x4*)(w2n + 0  + grp * 4);
    const f32x4 w2a1 = *(const f32x4*)(w2n + 16 + grp * 4);
    const f32x4 w2a2 = *(const f32x4*)(w2n + 32 + grp * 4);
    const f32x4 w2a3 = *(const f32x4*)(w2n + 48 + grp * 4);
    const f32x4 w2b0 = *(const f32x4*)(w2n + 64 + 0  + grp * 4);
    const f32x4 w2b1 = *(const f32x4*)(w2n + 64 + 16 + grp * 4);
    const f32x4 w2b2 = *(const f32x4*)(w2n + 64 + 32 + grp * 4);
    const f32x4 w2b3 = *(const f32x4*)(w2n + 64 + 48 + grp * 4);
    const float b20 = b2n[0], b21 = b2n[1];

    // ---- A-fragments: W1 rows in registers (lane: row=col, k = 32*KH + 8*grp + 0..7) ----
    const bf16x8* w1v = (const bf16x8*)w1s;
    const int sw = col & 7;
#define AF(RT,KH) w1v[((RT)*16 + col)*8 + (((KH)*4 + grp) ^ sw)]
    const bf16x8 A00 = AF(0,0), A01 = AF(0,1), A10 = AF(1,0), A11 = AF(1,1);
    const bf16x8 A20 = AF(2,0), A21 = AF(2,1), A30 = AF(3,0), A31 = AF(3,1);

    const size_t obase = (size_t)grp * PLANE + (size_t)n * NFULL;

    // ---- point 1024 first (wave 0), to get xp_last for the xp mirror ----
    if (wid == 0) {
        COMPUTE_TILE(s_alpha[1024])
        if (col == 0) {
            out[obase + 1024] = (grp == 0) ? xp : (grp == 1) ? yp : (grp == 2) ? xpp : ypp;
            if (grp == 0) s_xplast = xp;
        }
    }
    __syncthreads();
    const float xl2 = 2.0f * s_xplast;

    // ---- main loop: 16 iters/wave, 16 points each; covers b = 0..1023 ----
    #pragma unroll 1
    for (int it = 0; it < 16; ++it) {
        const int p = ((it * 4 + wid) << 4) + col;
        COMPUTE_TILE(s_alpha[p])
        const float vdir = (grp == 0) ? xp : (grp == 1) ? yp : (grp == 2) ? xpp : ypp;
        const float vmir = (grp == 0) ? (xl2 - xp)
                         : (grp == 1) ? yp
                         : (grp == 2) ? xpp : -ypp;
        out[obase + p] = vdir;
        out[obase + (2048 - p)] = vmir;
    }
}

extern "C" void kernel_launch(void* const* d_in, const int* in_sizes, int n_in,
                              void* d_out, int out_size, void* d_ws, size_t ws_size,
                              hipStream_t stream) {
    const float* alpha = (const float*)d_in[0];
    const float* w0    = (const float*)d_in[1];
    const float* w1    = (const float*)d_in[2];
    const float* w2    = (const float*)d_in[3];
    const float* b0    = (const float*)d_in[4];
    const float* b1    = (const float*)d_in[5];
    const float* b2    = (const float*)d_in[6];
    float* out = (float*)d_out;
    sofa_kernel<<<dim3(N_AB), dim3(256), 0, stream>>>(alpha, w0, w1, w2, b0, b1, b2, out);
}